// Round 1
// baseline (585.316 us; speedup 1.0000x reference)
//
#include <hip/hip_runtime.h>

#define DECAY 0.8f
#define EPS   1e-5f
#define HN    8
#define BB    8
#define NSEQ  2048
#define DD    64
#define CC    1024
#define NROW  (BB*NSEQ)   /* 16384 rows per head */

#define TN 128            /* rows per block tile */
#define TC 128            /* cols per chunk */
#define PAD 4

// ---------------- kernel 1: row sum-of-squares for x and embed ----------------
__global__ void sumsq_kernel(const float* __restrict__ x, const float* __restrict__ embed,
                             float* __restrict__ fsq, float* __restrict__ esq) {
    int tid = blockIdx.x * blockDim.x + threadIdx.x;
    const int totalF = HN * NROW;
    const int totalE = HN * CC;
    if (tid < totalF) {
        const float4* src = (const float4*)(x + (size_t)tid * DD);
        float s = 0.f;
        #pragma unroll
        for (int i = 0; i < DD/4; ++i) {
            float4 v = src[i];
            s = fmaf(v.x, v.x, s); s = fmaf(v.y, v.y, s);
            s = fmaf(v.z, v.z, s); s = fmaf(v.w, v.w, s);
        }
        fsq[tid] = s;
    } else if (tid < totalF + totalE) {
        int t = tid - totalF;
        const float4* src = (const float4*)(embed + (size_t)t * DD);
        float s = 0.f;
        #pragma unroll
        for (int i = 0; i < DD/4; ++i) {
            float4 v = src[i];
            s = fmaf(v.x, v.x, s); s = fmaf(v.y, v.y, s);
            s = fmaf(v.z, v.z, s); s = fmaf(v.w, v.w, s);
        }
        esq[t] = s;
    }
}

// ------------- kernel 2: dist GEMM + argmax + quantize + onehot + dist -------------
__global__ __launch_bounds__(256)
void dist_argmax_kernel(const float* __restrict__ x, const float* __restrict__ embed,
                        const float* __restrict__ fsq, const float* __restrict__ esq,
                        float* __restrict__ out_q, float* __restrict__ out_i,
                        float* __restrict__ out_oh, float* __restrict__ out_d) {
    __shared__ float xs[DD][TN + PAD];   // x tile, transposed:   xs[k][row]
    __shared__ float es[DD][TC + PAD];   // embed chunk, transp.: es[k][col]

    const int h   = blockIdx.y;
    const int n0  = blockIdx.x * TN;
    const int tid = threadIdx.x;

    const float* xh = x     + (size_t)h * NROW * DD;
    const float* eh = embed + (size_t)h * CC   * DD;

    // ---- stage x tile (transposed) ----
    {
        int f4 = tid & 15;        // which float4 along D
        int r0 = tid >> 4;        // 16 rows per pass
        #pragma unroll
        for (int it = 0; it < TN/16; ++it) {
            int r = r0 + it*16;
            float4 v = *(const float4*)(xh + (size_t)(n0 + r)*DD + f4*4);
            int d = f4*4;
            xs[d+0][r] = v.x; xs[d+1][r] = v.y; xs[d+2][r] = v.z; xs[d+3][r] = v.w;
        }
    }

    const int ty = tid >> 4;   // 0..15 -> rows ty*8 .. ty*8+7
    const int tx = tid & 15;   // 0..15 -> cols tx*8 .. tx*8+7 (within chunk)

    float fs[8];
    #pragma unroll
    for (int i = 0; i < 8; ++i) fs[i] = fsq[h*NROW + n0 + ty*8 + i];

    float bestv[8];
    int   besti[8];
    #pragma unroll
    for (int i = 0; i < 8; ++i) { bestv[i] = -3.4e38f; besti[i] = 0; }

    for (int c0 = 0; c0 < CC; c0 += TC) {
        __syncthreads();   // protect es from previous chunk's readers
        // ---- stage embed chunk (transposed) ----
        {
            int f4 = tid & 15;
            int r0 = tid >> 4;
            #pragma unroll
            for (int it = 0; it < TC/16; ++it) {
                int cc = r0 + it*16;
                float4 v = *(const float4*)(eh + (size_t)(c0 + cc)*DD + f4*4);
                int d = f4*4;
                es[d+0][cc] = v.x; es[d+1][cc] = v.y; es[d+2][cc] = v.z; es[d+3][cc] = v.w;
            }
        }
        __syncthreads();

        float acc[8][8];
        #pragma unroll
        for (int i = 0; i < 8; ++i)
            #pragma unroll
            for (int j = 0; j < 8; ++j) acc[i][j] = 0.f;

        #pragma unroll 4
        for (int k = 0; k < DD; ++k) {
            float a[8], b[8];
            *(float4*)&a[0] = *(const float4*)&xs[k][ty*8];
            *(float4*)&a[4] = *(const float4*)&xs[k][ty*8 + 4];
            *(float4*)&b[0] = *(const float4*)&es[k][tx*8];
            *(float4*)&b[4] = *(const float4*)&es[k][tx*8 + 4];
            #pragma unroll
            for (int i = 0; i < 8; ++i)
                #pragma unroll
                for (int j = 0; j < 8; ++j)
                    acc[i][j] = fmaf(a[i], b[j], acc[i][j]);
        }

        float eq[8];
        *(float4*)&eq[0] = *(const float4*)(esq + h*CC + c0 + tx*8);
        *(float4*)&eq[4] = *(const float4*)(esq + h*CC + c0 + tx*8 + 4);

        #pragma unroll
        for (int i = 0; i < 8; ++i) {
            int row = n0 + ty*8 + i;
            float dv[8];
            #pragma unroll
            for (int j = 0; j < 8; ++j)
                dv[j] = fmaf(2.f, acc[i][j], -(fs[i] + eq[j]));

            size_t ob = ((size_t)h*NROW + row)*CC + c0 + tx*8;
            *(float4*)(out_d + ob)     = make_float4(dv[0], dv[1], dv[2], dv[3]);
            *(float4*)(out_d + ob + 4) = make_float4(dv[4], dv[5], dv[6], dv[7]);
            float4 z = make_float4(0.f, 0.f, 0.f, 0.f);
            *(float4*)(out_oh + ob)     = z;
            *(float4*)(out_oh + ob + 4) = z;

            #pragma unroll
            for (int j = 0; j < 8; ++j) {
                if (dv[j] > bestv[i]) { bestv[i] = dv[j]; besti[i] = c0 + tx*8 + j; }
            }
        }
    }

    __syncthreads();   // all one-hot zeros for this tile are issued/drained

    // ---- argmax reduce across the 16 tx lanes of each group; write outputs ----
    #pragma unroll
    for (int i = 0; i < 8; ++i) {
        float v  = bestv[i];
        int   id = besti[i];
        #pragma unroll
        for (int off = 8; off >= 1; off >>= 1) {
            float ov = __shfl_xor(v, off, 64);
            int   oi = __shfl_xor(id, off, 64);
            if (ov > v || (ov == v && oi < id)) { v = ov; id = oi; }
        }
        int row = n0 + ty*8 + i;
        // quantize: 16 lanes copy 64 floats of embed row `id`
        float4 qv = *(const float4*)(eh + (size_t)id*DD + tx*4);
        *(float4*)(out_q + ((size_t)h*NROW + row)*DD + tx*4) = qv;
        if (tx == 0) {
            out_i[(size_t)h*NROW + row] = (float)id;
            out_oh[((size_t)h*NROW + row)*CC + id] = 1.0f;
        }
    }
}

// ------------- kernel 3: deterministic EMA updates -------------
__global__ __launch_bounds__(64)
void ema_kernel(const float* __restrict__ x, const float* __restrict__ embed_avg,
                const float* __restrict__ cluster_size, const float* __restrict__ ind_f,
                float* __restrict__ out_cs, float* __restrict__ out_ea,
                float* __restrict__ out_norm) {
    const int h    = blockIdx.y;
    const int c    = blockIdx.x;
    const int lane = threadIdx.x;

    const float* cs_h = cluster_size + h*CC;
    // sum of cluster_size row (all lanes end with S)
    float s = 0.f;
    #pragma unroll
    for (int i = 0; i < CC/64; ++i) s += cs_h[lane + i*64];
    #pragma unroll
    for (int off = 32; off >= 1; off >>= 1) s += __shfl_xor(s, off, 64);

    const float* xh   = x     + (size_t)h * NROW * DD;
    const float* indh = ind_f + (size_t)h * NROW;

    float sum_d = 0.f;
    int   cnt   = 0;
    for (int chunk = 0; chunk < NROW/64; ++chunk) {
        int myidx = (int)indh[chunk*64 + lane];
        unsigned long long m = __ballot(myidx == c);
        while (m) {
            int t = __ffsll(m) - 1;
            m &= m - 1;
            int n = chunk*64 + t;
            sum_d += xh[(size_t)n*DD + lane];
            cnt++;
        }
    }

    float csn  = cs_h[c]*DECAY + (float)cnt*(1.f - DECAY);
    float ea   = embed_avg[((size_t)h*CC + c)*DD + lane]*DECAY + sum_d*(1.f - DECAY);
    float ntot = s*DECAY + (1.f - DECAY)*(float)NROW;
    float css  = (csn + EPS) / (ntot + (float)CC*EPS) * ntot;

    out_ea  [((size_t)h*CC + c)*DD + lane] = ea;
    out_norm[((size_t)h*CC + c)*DD + lane] = ea / css;
    if (lane == 0) out_cs[h*CC + c] = csn;
}

extern "C" void kernel_launch(void* const* d_in, const int* in_sizes, int n_in,
                              void* d_out, int out_size, void* d_ws, size_t ws_size,
                              hipStream_t stream) {
    const float* x            = (const float*)d_in[0];
    const float* embed        = (const float*)d_in[1];
    const float* embed_avg    = (const float*)d_in[2];
    const float* cluster_size = (const float*)d_in[3];

    float* out = (float*)d_out;
    float* fsq = (float*)d_ws;
    float* esq = fsq + (size_t)HN * NROW;

    float* out_q    = out;
    float* out_i    = out_q    + (size_t)HN * NROW * DD;
    float* out_oh   = out_i    + (size_t)HN * NROW;
    float* out_d    = out_oh   + (size_t)HN * NROW * CC;
    float* out_norm = out_d    + (size_t)HN * NROW * CC;
    float* out_ea   = out_norm + (size_t)HN * CC * DD;
    float* out_cs   = out_ea   + (size_t)HN * CC * DD;

    {
        int total = HN*NROW + HN*CC;
        sumsq_kernel<<<(total + 255)/256, 256, 0, stream>>>(x, embed, fsq, esq);
    }
    {
        dim3 g(NROW/TN, HN);
        dist_argmax_kernel<<<g, 256, 0, stream>>>(x, embed, fsq, esq,
                                                  out_q, out_i, out_oh, out_d);
    }
    {
        dim3 g(CC, HN);
        ema_kernel<<<g, 64, 0, stream>>>(x, embed_avg, cluster_size, out_i,
                                         out_cs, out_ea, out_norm);
    }
}

// Round 3
// 579.567 us; speedup vs baseline: 1.0099x; 1.0099x over previous
//
#include <hip/hip_runtime.h>

#define DECAY 0.8f
#define EPS   1e-5f
#define HN    8
#define BB    8
#define NSEQ  2048
#define DD    64
#define CC    1024
#define NROW  (BB*NSEQ)   /* 16384 rows per head */

#define LS 128            /* LDS row stride (floats) */
#define XS(k,r) xs[(k)*LS + (r)]
#define ES(k,c) es[(k)*LS + (c)]

// ---------------- kernel 1: row sum-of-squares for x and embed ----------------
__global__ void sumsq_kernel(const float* __restrict__ x, const float* __restrict__ embed,
                             float* __restrict__ fsq, float* __restrict__ esq) {
    int tid = blockIdx.x * blockDim.x + threadIdx.x;
    const int totalF = HN * NROW;
    const int totalE = HN * CC;
    if (tid < totalF) {
        const float4* src = (const float4*)(x + (size_t)tid * DD);
        float s = 0.f;
        #pragma unroll
        for (int i = 0; i < DD/4; ++i) {
            float4 v = src[i];
            s = fmaf(v.x, v.x, s); s = fmaf(v.y, v.y, s);
            s = fmaf(v.z, v.z, s); s = fmaf(v.w, v.w, s);
        }
        fsq[tid] = s;
    } else if (tid < totalF + totalE) {
        int t = tid - totalF;
        const float4* src = (const float4*)(embed + (size_t)t * DD);
        float s = 0.f;
        #pragma unroll
        for (int i = 0; i < DD/4; ++i) {
            float4 v = src[i];
            s = fmaf(v.x, v.x, s); s = fmaf(v.y, v.y, s);
            s = fmaf(v.z, v.z, s); s = fmaf(v.w, v.w, s);
        }
        esq[t] = s;
    }
}

// ------------- kernel 2: fp32 dist GEMM + argmax + quantize + onehot + dist -------------
__global__ __launch_bounds__(256, 2)
void dist_fp32_kernel(const float* __restrict__ x, const float* __restrict__ embed,
                      const float* __restrict__ fsq, const float* __restrict__ esq,
                      float* __restrict__ out_q, float* __restrict__ out_i,
                      float* __restrict__ out_oh, float* __restrict__ out_d) {
    __shared__ float xs[64 * LS];   // [k][row], transposed x tile
    __shared__ float es[64 * LS];   // [k][col], transposed embed chunk

    const int h   = blockIdx.y;
    const int n0  = blockIdx.x * 128;
    const int tid = threadIdx.x;
    const int ty  = tid >> 4;       // 0..15 -> rows ty*8 .. ty*8+7
    const int tx  = tid & 15;       // cols {tx*4..+3} and {64+tx*4..+3}

    const float* xh_   = x     + (size_t)h * NROW * DD;
    const float* eh_   = embed + (size_t)h * CC   * DD;
    const float* esq_h = esq   + h * CC;

    const int g4 = (tid & 31) * 4;  // group of 4 rows/cols to transpose
    const int k0 = (tid >> 5) * 8;  // group of 8 k's

    // ---- stage x tile (4x4 register transpose -> b128 LDS writes) ----
    {
        float4 v[2][4];
        #pragma unroll
        for (int t = 0; t < 2; ++t)
            #pragma unroll
            for (int i = 0; i < 4; ++i)
                v[t][i] = *(const float4*)(xh_ + (size_t)(n0 + g4 + i) * DD + k0 + t*4);
        #pragma unroll
        for (int t = 0; t < 2; ++t) {
            *(float4*)&XS(k0+t*4+0, g4) = make_float4(v[t][0].x, v[t][1].x, v[t][2].x, v[t][3].x);
            *(float4*)&XS(k0+t*4+1, g4) = make_float4(v[t][0].y, v[t][1].y, v[t][2].y, v[t][3].y);
            *(float4*)&XS(k0+t*4+2, g4) = make_float4(v[t][0].z, v[t][1].z, v[t][2].z, v[t][3].z);
            *(float4*)&XS(k0+t*4+3, g4) = make_float4(v[t][0].w, v[t][1].w, v[t][2].w, v[t][3].w);
        }
    }
    // ---- stage embed chunk 0 ----
    {
        float4 v[2][4];
        #pragma unroll
        for (int t = 0; t < 2; ++t)
            #pragma unroll
            for (int i = 0; i < 4; ++i)
                v[t][i] = *(const float4*)(eh_ + (size_t)(g4 + i) * DD + k0 + t*4);
        #pragma unroll
        for (int t = 0; t < 2; ++t) {
            *(float4*)&ES(k0+t*4+0, g4) = make_float4(v[t][0].x, v[t][1].x, v[t][2].x, v[t][3].x);
            *(float4*)&ES(k0+t*4+1, g4) = make_float4(v[t][0].y, v[t][1].y, v[t][2].y, v[t][3].y);
            *(float4*)&ES(k0+t*4+2, g4) = make_float4(v[t][0].z, v[t][1].z, v[t][2].z, v[t][3].z);
            *(float4*)&ES(k0+t*4+3, g4) = make_float4(v[t][0].w, v[t][1].w, v[t][2].w, v[t][3].w);
        }
    }
    asm volatile("s_waitcnt lgkmcnt(0)" ::: "memory");
    __builtin_amdgcn_s_barrier();

    float fs[8];
    #pragma unroll
    for (int i = 0; i < 8; ++i) fs[i] = fsq[h*NROW + n0 + ty*8 + i];

    float bestv[8];
    int   besti[8];
    #pragma unroll
    for (int i = 0; i < 8; ++i) { bestv[i] = -3.4e38f; besti[i] = 0; }

    #pragma unroll 1
    for (int ci = 0; ci < 8; ++ci) {
        const int c0 = ci * 128;

        // prefetch next chunk into registers (flies under the FMA phase)
        float4 ev[2][4];
        if (ci < 7) {
            #pragma unroll
            for (int t = 0; t < 2; ++t)
                #pragma unroll
                for (int i = 0; i < 4; ++i)
                    ev[t][i] = *(const float4*)(eh_ + (size_t)(c0 + 128 + g4 + i) * DD + k0 + t*4);
        }

        float acc[8][8];
        #pragma unroll
        for (int i = 0; i < 8; ++i)
            #pragma unroll
            for (int j = 0; j < 8; ++j) acc[i][j] = 0.f;

        #pragma unroll 4
        for (int k = 0; k < 64; ++k) {
            float a[8], b[8];
            *(float4*)&a[0] = *(const float4*)&XS(k, ty*8);
            *(float4*)&a[4] = *(const float4*)&XS(k, ty*8 + 4);
            *(float4*)&b[0] = *(const float4*)&ES(k, tx*4);
            *(float4*)&b[4] = *(const float4*)&ES(k, 64 + tx*4);
            #pragma unroll
            for (int i = 0; i < 8; ++i)
                #pragma unroll
                for (int j = 0; j < 8; ++j)
                    acc[i][j] = fmaf(a[i], b[j], acc[i][j]);
        }

        float eq[8];
        *(float4*)&eq[0] = *(const float4*)(esq_h + c0 + tx*4);
        *(float4*)&eq[4] = *(const float4*)(esq_h + c0 + 64 + tx*4);

        #pragma unroll
        for (int i = 0; i < 8; ++i) {
            int row = n0 + ty*8 + i;
            float dv[8];
            #pragma unroll
            for (int j = 0; j < 8; ++j)
                dv[j] = fmaf(2.f, acc[i][j], -(fs[i] + eq[j]));

            size_t rb = ((size_t)h*NROW + row)*CC + c0;
            *(float4*)(out_d + rb + tx*4)       = make_float4(dv[0], dv[1], dv[2], dv[3]);
            *(float4*)(out_d + rb + 64 + tx*4)  = make_float4(dv[4], dv[5], dv[6], dv[7]);
            float4 z = make_float4(0.f, 0.f, 0.f, 0.f);
            *(float4*)(out_oh + rb + tx*4)      = z;
            *(float4*)(out_oh + rb + 64 + tx*4) = z;

            #pragma unroll
            for (int j = 0; j < 4; ++j) {
                if (dv[j] > bestv[i]) { bestv[i] = dv[j]; besti[i] = c0 + tx*4 + j; }
            }
            #pragma unroll
            for (int j = 4; j < 8; ++j) {
                if (dv[j] > bestv[i]) { bestv[i] = dv[j]; besti[i] = c0 + 64 + tx*4 + (j-4); }
            }
        }

        if (ci < 7) {
            // all waves done reading es (reads consumed; lgkmcnt==0 here)
            asm volatile("s_waitcnt lgkmcnt(0)" ::: "memory");
            __builtin_amdgcn_s_barrier();
            #pragma unroll
            for (int t = 0; t < 2; ++t) {
                *(float4*)&ES(k0+t*4+0, g4) = make_float4(ev[t][0].x, ev[t][1].x, ev[t][2].x, ev[t][3].x);
                *(float4*)&ES(k0+t*4+1, g4) = make_float4(ev[t][0].y, ev[t][1].y, ev[t][2].y, ev[t][3].y);
                *(float4*)&ES(k0+t*4+2, g4) = make_float4(ev[t][0].z, ev[t][1].z, ev[t][2].z, ev[t][3].z);
                *(float4*)&ES(k0+t*4+3, g4) = make_float4(ev[t][0].w, ev[t][1].w, ev[t][2].w, ev[t][3].w);
            }
            asm volatile("s_waitcnt lgkmcnt(0)" ::: "memory");
            __builtin_amdgcn_s_barrier();
        }
    }

    // drain this wave's one-hot zero stores before writing the 1.0s
    asm volatile("s_waitcnt vmcnt(0)" ::: "memory");

    // ---- argmax reduce across the 16 tx lanes sharing each row; write outputs ----
    #pragma unroll
    for (int i = 0; i < 8; ++i) {
        float v  = bestv[i];
        int   id = besti[i];
        #pragma unroll
        for (int off = 8; off >= 1; off >>= 1) {
            float ov = __shfl_xor(v, off, 64);
            int   oi = __shfl_xor(id, off, 64);
            if (ov > v || (ov == v && oi < id)) { v = ov; id = oi; }
        }
        int row = n0 + ty*8 + i;
        float4 qv = *(const float4*)(eh_ + (size_t)id*DD + tx*4);
        *(float4*)(out_q + ((size_t)h*NROW + row)*DD + tx*4) = qv;
        if (tx == 0) {
            out_i[(size_t)h*NROW + row] = (float)id;
            out_oh[((size_t)h*NROW + row)*CC + id] = 1.0f;
        }
    }
}

// ------------- kernel 3: deterministic EMA updates -------------
__global__ __launch_bounds__(64)
void ema_kernel(const float* __restrict__ x, const float* __restrict__ embed_avg,
                const float* __restrict__ cluster_size, const float* __restrict__ ind_f,
                float* __restrict__ out_cs, float* __restrict__ out_ea,
                float* __restrict__ out_norm) {
    const int h    = blockIdx.y;
    const int c    = blockIdx.x;
    const int lane = threadIdx.x;

    const float* cs_h = cluster_size + h*CC;
    float s = 0.f;
    #pragma unroll
    for (int i = 0; i < CC/64; ++i) s += cs_h[lane + i*64];
    #pragma unroll
    for (int off = 32; off >= 1; off >>= 1) s += __shfl_xor(s, off, 64);

    const float* xh   = x     + (size_t)h * NROW * DD;
    const float* indh = ind_f + (size_t)h * NROW;

    float sum_d = 0.f;
    int   cnt   = 0;
    for (int chunk = 0; chunk < NROW/64; ++chunk) {
        int myidx = (int)indh[chunk*64 + lane];
        unsigned long long m = __ballot(myidx == c);
        while (m) {
            int t = __ffsll(m) - 1;
            m &= m - 1;
            int n = chunk*64 + t;
            sum_d += xh[(size_t)n*DD + lane];
            cnt++;
        }
    }

    float csn  = cs_h[c]*DECAY + (float)cnt*(1.f - DECAY);
    float ea   = embed_avg[((size_t)h*CC + c)*DD + lane]*DECAY + sum_d*(1.f - DECAY);
    float ntot = s*DECAY + (1.f - DECAY)*(float)NROW;
    float css  = (csn + EPS) / (ntot + (float)CC*EPS) * ntot;

    out_ea  [((size_t)h*CC + c)*DD + lane] = ea;
    out_norm[((size_t)h*CC + c)*DD + lane] = ea / css;
    if (lane == 0) out_cs[h*CC + c] = csn;
}

extern "C" void kernel_launch(void* const* d_in, const int* in_sizes, int n_in,
                              void* d_out, int out_size, void* d_ws, size_t ws_size,
                              hipStream_t stream) {
    const float* x            = (const float*)d_in[0];
    const float* embed        = (const float*)d_in[1];
    const float* embed_avg    = (const float*)d_in[2];
    const float* cluster_size = (const float*)d_in[3];

    float* out = (float*)d_out;
    float* fsq = (float*)d_ws;
    float* esq = fsq + (size_t)HN * NROW;

    float* out_q    = out;
    float* out_i    = out_q    + (size_t)HN * NROW * DD;
    float* out_oh   = out_i    + (size_t)HN * NROW;
    float* out_d    = out_oh   + (size_t)HN * NROW * CC;
    float* out_norm = out_d    + (size_t)HN * NROW * CC;
    float* out_ea   = out_norm + (size_t)HN * CC * DD;
    float* out_cs   = out_ea   + (size_t)HN * CC * DD;

    {
        int total = HN*NROW + HN*CC;
        sumsq_kernel<<<(total + 255)/256, 256, 0, stream>>>(x, embed, fsq, esq);
    }
    {
        dim3 g(NROW/128, HN);
        dist_fp32_kernel<<<g, 256, 0, stream>>>(x, embed, fsq, esq,
                                                out_q, out_i, out_oh, out_d);
    }
    {
        dim3 g(CC, HN);
        ema_kernel<<<g, 64, 0, stream>>>(x, embed_avg, cluster_size, out_i,
                                         out_cs, out_ea, out_norm);
    }
}